// Round 10
// baseline (902.447 us; speedup 1.0000x reference)
//
#include <hip/hip_runtime.h>
#include <math.h>

#define PI_F 3.14159265358979323846f
#define KS 258   // padded column count of half-spectrum G (k in [0,256], stride 258)

typedef float f2 __attribute__((ext_vector_type(2)));

// ---------------------------------------------------------------- FFT core
// Two radix-2 stages fused per LDS round trip; u in [0,128) indexes the
// butterfly group. Called with re/im pointing at a 512-float segment.
// All threads of the block must call (uniform barriers).
__device__ __forceinline__ void fft512(float* re, float* im,
                                       const float* twr, const float* twi, int u) {
#pragma unroll
  for (int s = 0; s < 8; s += 2) {
    __syncthreads();
    {
      int h  = 1 << s;
      int j  = u & (h - 1);
      int a  = ((u >> s) << (s + 2)) + j;
      int i0 = a, i1 = a + h, i2 = a + 2 * h, i3 = a + 3 * h;
      float e0r = re[i0], e0i = im[i0];
      float e1r = re[i1], e1i = im[i1];
      float e2r = re[i2], e2i = im[i2];
      float e3r = re[i3], e3i = im[i3];
      int tis = j << (8 - s);
      float wsr = twr[tis], wsi = twi[tis];
      float t1r = e1r * wsr - e1i * wsi, t1i = e1r * wsi + e1i * wsr;
      float t3r = e3r * wsr - e3i * wsi, t3i = e3r * wsi + e3i * wsr;
      float b0r = e0r + t1r, b0i = e0i + t1i;
      float b1r = e0r - t1r, b1i = e0i - t1i;
      float b2r = e2r + t3r, b2i = e2i + t3i;
      float b3r = e2r - t3r, b3i = e2i - t3i;
      int ti0 = j << (7 - s);
      int ti1 = (j + h) << (7 - s);
      float w0r = twr[ti0], w0i = twi[ti0];
      float w1r = twr[ti1], w1i = twi[ti1];
      float u2r = b2r * w0r - b2i * w0i, u2i = b2r * w0i + b2i * w0r;
      float u3r = b3r * w1r - b3i * w1i, u3i = b3r * w1i + b3i * w1r;
      re[i0] = b0r + u2r; im[i0] = b0i + u2i;
      re[i2] = b0r - u2r; im[i2] = b0i - u2i;
      re[i1] = b1r + u3r; im[i1] = b1i + u3i;
      re[i3] = b1r - u3r; im[i3] = b1i - u3i;
    }
  }
  __syncthreads();
  {
#pragma unroll
    for (int k = 0; k < 2; ++k) {
      int i1 = u + k * 128;
      int i2 = i1 + 256;
      float wr = twr[i1], wi = twi[i1];
      float ur = re[i1], ui = im[i1];
      float vr = re[i2], vi = im[i2];
      float tr = vr * wr - vi * wi;
      float tq = vr * wi + vi * wr;
      re[i1] = ur + tr; im[i1] = ui + tq;
      re[i2] = ur - tr; im[i2] = ui - tq;
    }
  }
  __syncthreads();
}

__device__ __forceinline__ void init_tw(float* twr, float* twi, int t) {
  float s, c;
  sincosf(-2.0f * PI_F * (float)t * (1.0f / 512.0f), &s, &c);
  twr[t] = c; twi[t] = s;
}

// ------------------------------------------------- K1: gray + paired-row FFT (Hermitian pack)
// TWO packed FFTs per block (4 image rows), f = t>>7 selects the FFT.
__global__ __launch_bounds__(256) void k_rowfft(const float* __restrict__ x,
                                                float2* __restrict__ G) {
  __shared__ float re[1024], im[1024], twr[256], twi[256];
  int t = threadIdx.x;
  int q = blockIdx.x;          // 0..127
  int b = blockIdx.y;
  int f = t >> 7, u = t & 127;
  int r0 = 4 * q;
  const float* xb = x + ((size_t)b * 3 * 512 + r0) * 512;
  const float* xr = xb + (2 * f) * 512;   // row pair base for this FFT
  float* reb = re + 512 * f;
  float* imb = im + 512 * f;
#pragma unroll
  for (int j = 0; j < 4; ++j) {
    int p = u + 128 * j;
    float a = 0.299f * xr[p]        + 0.587f * xr[262144 + p]  + 0.114f * xr[524288 + p];
    float c = 0.299f * xr[512 + p]  + 0.587f * xr[262656 + p]  + 0.114f * xr[524800 + p];
    int rv = __brev((unsigned)p) >> 23;
    reb[rv] = a; imb[rv] = c;
  }
  init_tw(twr, twi, t);
  fft512(reb, imb, twr, twi, u);
  int r0p = r0 + 2 * f;
  float2* G0 = G + ((size_t)b * 512 + r0p) * KS;
  float2* G1 = G0 + KS;
  for (int k = u; k <= 256; k += 128) {
    int mk = (512 - k) & 511;
    float zr = reb[k], zi = imb[k];
    float mr = reb[mk], mi = imb[mk];
    G0[k] = make_float2(0.5f * (zr + mr), 0.5f * (zi - mi));
    G1[k] = make_float2(0.5f * (zi + mi), 0.5f * (mr - zr));
  }
}

// ------------------------------------------------- K1.5: out-of-place transpose G -> GT
__global__ __launch_bounds__(256) void k_transpose(const float2* __restrict__ G,
                                                   float2* __restrict__ GT) {
  __shared__ float2 ta[32][33];
  int kt = blockIdx.x, rt = blockIdx.y, b = blockIdx.z;
  int tx = threadIdx.x, ty = threadIdx.y;
  int k0 = kt * 32, r0 = rt * 32;
  const float2* Gb = G + (size_t)b * 512 * KS;
  float2* GTb = GT + (size_t)b * KS * 512;
#pragma unroll
  for (int i = 0; i < 32; i += 8) {
    int k = k0 + tx;
    float2 v = make_float2(0.0f, 0.0f);
    if (k < KS) v = Gb[(size_t)(r0 + ty + i) * KS + k];
    ta[ty + i][tx] = v;
  }
  __syncthreads();
#pragma unroll
  for (int i = 0; i < 32; i += 8) {
    int k = k0 + ty + i;
    if (k < KS) GTb[(size_t)k * 512 + r0 + tx] = ta[tx][ty + i];
  }
}

// ------------------------------------------------- K2: column FFT + mag/log1p/fftshift + mirror + stats
// TWO columns per block; tail column kc=257 masked (no S writes, weight 0).
__global__ __launch_bounds__(256) void k_colfft(const float2* __restrict__ GT,
                                                float* __restrict__ S,
                                                double* __restrict__ stats) {
  __shared__ float re[1024], im[1024], twr[256], twi[256];
  __shared__ float ws1[4], ws2[4];
  int t  = threadIdx.x;
  int b  = blockIdx.y;
  int f = t >> 7, u = t & 127;
  int kc = 2 * blockIdx.x + f;
  bool valid = (kc <= 256);
  const float2* Gc = GT + ((size_t)b * KS + kc) * 512;
  float* reb = re + 512 * f;
  float* imb = im + 512 * f;
#pragma unroll
  for (int j = 0; j < 4; ++j) {
    int p = u + 128 * j;
    float2 v = Gc[p];
    int rv = __brev((unsigned)p) >> 23;
    reb[rv] = v.x; imb[rv] = v.y;
  }
  init_tw(twr, twi, t);
  fft512(reb, imb, twr, twi, u);
  int vrow = (kc + 256) & 511;
  bool mir = (kc >= 1) && (kc <= 255);
  float* Sb = S + (size_t)b * 262144;
  float s1 = 0.0f, s2 = 0.0f;
#pragma unroll
  for (int j = 0; j < 4; ++j) {
    int k = u + 128 * j;
    float mm = log1pf(sqrtf(reb[k] * reb[k] + imb[k] * imb[k]));
    if (valid) {
      Sb[(size_t)vrow * 512 + ((k + 256) & 511)] = mm;
      if (mir) Sb[(size_t)(256 - kc) * 512 + ((256 - k) & 511)] = mm;
      s1 += mm; s2 += mm * mm;
    }
  }
  float w = mir ? 2.0f : (valid ? 1.0f : 0.0f);
  s1 *= w; s2 *= w;
#pragma unroll
  for (int off = 32; off > 0; off >>= 1) {
    s1 += __shfl_down(s1, off);
    s2 += __shfl_down(s2, off);
  }
  int wvid = t >> 6;
  if ((t & 63) == 0) { ws1[wvid] = s1; ws2[wvid] = s2; }
  __syncthreads();
  if (t == 0) {
    float a = ws1[0] + ws1[1] + ws1[2] + ws1[3];
    float c = ws2[0] + ws2[1] + ws2[2] + ws2[3];
    atomicAdd(&stats[2 * b],     (double)a);
    atomicAdd(&stats[2 * b + 1], (double)c);
  }
}

__global__ void k_zero_stats(double* stats) {
  stats[threadIdx.x] = 0.0;
}

__global__ void k_stats(const double* __restrict__ stats, float2* __restrict__ muinv) {
  int i = threadIdx.x;  // 64
  double n  = 262144.0;
  double mu = stats[2 * i] / n;
  double va = stats[2 * i + 1] / n - mu * mu;
  if (va < 0.0) va = 0.0;
  double sd = sqrt(va);
  muinv[i] = make_float2((float)mu, (float)(1.0 / (sd + 1e-8)));
}

// ------------------------------------------------- K4: conv1(5x5,s2,p2) + BN + ReLU + maxpool2
#define TS1 68
__global__ __launch_bounds__(256) void k_conv1(
    const float* __restrict__ S, const float2* __restrict__ muinv,
    const float* __restrict__ w, const float* __restrict__ cb,
    const float* __restrict__ g, const float* __restrict__ bb,
    const float* __restrict__ bm, const float* __restrict__ bv,
    float* __restrict__ h1) {
  __shared__ float tile[67 * TS1];
  int b = blockIdx.y;
  int by = blockIdx.x >> 3, bx = blockIdx.x & 7;
  int y0 = by * 16, x0 = bx * 16;
  int h0 = 4 * y0 - 2, w0 = 4 * x0 - 2;
  float2 mi = muinv[b];
  const float* Sb = S + (size_t)b * 262144;
  for (int idx = threadIdx.x; idx < 67 * 67; idx += 256) {
    int wl = idx / 67, hl = idx - wl * 67;
    int hh = h0 + hl, ww = w0 + wl;
    float val = 0.0f;
    if (hh >= 0 && hh < 512 && ww >= 0 && ww < 512)
      val = (Sb[(size_t)ww * 512 + hh] - mi.x) * mi.y;
    tile[wl * TS1 + hl] = val;
  }
  __syncthreads();
  int ty = threadIdx.x >> 4, tx = threadIdx.x & 15;
  float in[7][7];
#pragma unroll
  for (int j = 0; j < 7; ++j)
#pragma unroll
    for (int i = 0; i < 7; ++i)
      in[i][j] = tile[(4 * tx + j) * TS1 + 4 * ty + i];
  f2 P[7][5];
#pragma unroll
  for (int r = 0; r < 7; ++r)
#pragma unroll
    for (int c = 0; c < 5; ++c)
      P[r][c] = (f2){in[r][c], in[r][c + 2]};
  int Y = y0 + ty, X = x0 + tx;
  for (int oc = 0; oc < 32; ++oc) {
    const float* wo = w + oc * 25;
    f2 aA = (f2){0.0f, 0.0f};
    f2 aB = (f2){0.0f, 0.0f};
#pragma unroll
    for (int dy = 0; dy < 5; ++dy)
#pragma unroll
      for (int dx = 0; dx < 5; ++dx) {
        float wv = wo[dy * 5 + dx];
        f2 wv2 = (f2){wv, wv};
        aA = __builtin_elementwise_fma(wv2, P[dy][dx],     aA);
        aB = __builtin_elementwise_fma(wv2, P[dy + 2][dx], aB);
      }
    float m   = fmaxf(fmaxf(aA.x, aA.y), fmaxf(aB.x, aB.y));
    float inv = g[oc] / sqrtf(bv[oc] + 1e-5f);
    float sh  = cb[oc] * inv + bb[oc] - bm[oc] * inv;
    h1[(((size_t)b * 32 + oc) * 128 + Y) * 128 + X] = fmaxf(m * inv + sh, 0.0f);
  }
}

// ------------------------------------------------- K5: conv2(3x3,s2,p1,32->64) + BN + ReLU + maxpool2
// v8: T14 + pk-FMA + (a) staging offsets precomputed ONCE (ict-invariant:
// all div/mod hoisted out of the phase loop; srco=-1 encodes OOB) and
// (b) double-buffered LDS -> ONE barrier per phase (race-safe: between
// consecutive barriers, WRITER targets the opposite buffer from any
// in-flight COMPUTE reads; the overwritten buffer was last read before
// the previous barrier).
#define TS2 36
__global__ __launch_bounds__(512) void k_conv2(
    const float* __restrict__ h1, const float* __restrict__ w,
    const float* __restrict__ cb, const float* __restrict__ g,
    const float* __restrict__ bb, const float* __restrict__ bm,
    const float* __restrict__ bv, float* __restrict__ h2) {
  __shared__ __attribute__((aligned(16))) float tile[2][8 * 33 * TS2];  // 76032 B
  int tid = threadIdx.x;
  int b = blockIdx.y;
  int rt = blockIdx.x >> 2, ct = blockIdx.x & 3;
  int ty0 = rt * 16, tx0 = ct * 16;
  int wv = tid >> 6;
  int lane = tid & 63;
  int qy = lane >> 3, qx = lane & 7;
  int iy0 = 2 * ty0 - 1, ix0 = 2 * tx0 - 1;
  int ocbase = wv * 8;
  f2 accA[8], accB[8];
#pragma unroll
  for (int q = 0; q < 8; ++q) {
    accA[q] = (f2){0.0f, 0.0f};
    accB[q] = (f2){0.0f, 0.0f};
  }

  // ---- precompute staging offsets (ict-invariant) ----
  int dsto[18], srco[18];
#pragma unroll
  for (int k = 0; k < 17; ++k) {
    int idx = tid + 512 * k;
    int ic = idx / 1089;
    int rem = idx - ic * 1089;
    int rr = rem / 33, cc = rem - rr * 33;
    int iy = iy0 + rr, ix = ix0 + cc;
    dsto[k] = (ic * 33 + rr) * TS2 + cc;
    srco[k] = (iy >= 0 && iy < 128 && ix >= 0 && ix < 128)
                  ? ((ic * 128 + iy) * 128 + ix) : -1;
  }
  {
    int idx = 8704 + tid;   // tail: only tid<8 writes
    int ic = idx / 1089;
    int rem = idx - ic * 1089;
    int rr = rem / 33, cc = rem - rr * 33;
    int iy = iy0 + rr, ix = ix0 + cc;
    dsto[17] = (ic * 33 + rr) * TS2 + cc;
    srco[17] = (tid < 8 && iy >= 0 && iy < 128 && ix >= 0 && ix < 128)
                   ? ((ic * 128 + iy) * 128 + ix) : -1;
  }
  const float* h1b = h1 + (size_t)b * 32 * 16384;

  float rv[18];
#define C2_LOADR(ICT)                                                          \
  {                                                                            \
    _Pragma("unroll")                                                          \
    for (int k = 0; k < 18; ++k) {                                             \
      float v = 0.0f;                                                          \
      if (srco[k] >= 0) v = h1b[(ICT) * 131072 + srco[k]];                     \
      rv[k] = v;                                                               \
    }                                                                          \
  }

#define C2_WRITER(BUF)                                                         \
  {                                                                            \
    _Pragma("unroll")                                                          \
    for (int k = 0; k < 17; ++k) tile[BUF][dsto[k]] = rv[k];                   \
    if (tid < 8) tile[BUF][dsto[17]] = rv[17];                                 \
  }

  C2_LOADR(0);
  for (int ict = 0; ict < 4; ++ict) {
    int bs = ict & 1;
    C2_WRITER(bs);                 // waits vmcnt for rv (issued a phase ago)
    if (ict < 3) C2_LOADR(ict + 1);
    __syncthreads();               // single barrier per phase (dbuf)
    const float* tb = tile[bs];
    int rbase = 4 * qy, cbase = 4 * qx;
#pragma unroll
    for (int ic = 0; ic < 8; ++ic) {
      f2 P[5][3];
#pragma unroll
      for (int i = 0; i < 5; ++i) {
        int base = (ic * 33 + rbase + i) * TS2 + cbase;
        float4 a = *reinterpret_cast<const float4*>(&tb[base]);
        float b4 = tb[base + 4];
        P[i][0] = (f2){a.x, a.z};
        P[i][1] = (f2){a.y, a.w};
        P[i][2] = (f2){a.z, b4};
      }
      const float* wic = w + ((size_t)ocbase * 32 + ict * 8 + ic) * 9;
#pragma unroll
      for (int q = 0; q < 8; ++q) {
        const float* wo = wic + (size_t)q * 32 * 9;
#pragma unroll
        for (int dy = 0; dy < 3; ++dy)
#pragma unroll
          for (int dx = 0; dx < 3; ++dx) {
            float wvv = wo[dy * 3 + dx];
            f2 wv2 = (f2){wvv, wvv};
            accA[q] = __builtin_elementwise_fma(wv2, P[dy][dx],     accA[q]);
            accB[q] = __builtin_elementwise_fma(wv2, P[dy + 2][dx], accB[q]);
          }
      }
    }
  }
  int Yp = (ty0 >> 1) + qy, Xp = (tx0 >> 1) + qx;
#pragma unroll
  for (int q = 0; q < 8; ++q) {
    int oc = ocbase + q;
    float m   = fmaxf(fmaxf(accA[q].x, accA[q].y), fmaxf(accB[q].x, accB[q].y));
    float inv = g[oc] / sqrtf(bv[oc] + 1e-5f);
    float sh  = cb[oc] * inv + bb[oc] - bm[oc] * inv;
    h2[(((size_t)b * 64 + oc) * 32 + Yp) * 32 + Xp] = fmaxf(m * inv + sh, 0.0f);
  }
#undef C2_LOADR
#undef C2_WRITER
}

// ------------------------------------------------- K6: conv3(3x3,s2,p1,64->128) + BN + ReLU + GAP
#define TS3 34
__global__ __launch_bounds__(256) void k_conv3(
    const float* __restrict__ h2, const float* __restrict__ w,
    const float* __restrict__ cb, const float* __restrict__ g,
    const float* __restrict__ bb, const float* __restrict__ bm,
    const float* __restrict__ bv, float* __restrict__ gap) {
  __shared__ __attribute__((aligned(16))) float tile[8 * 33 * TS3];
  __shared__ float ws3[8][4];
  int tid = threadIdx.x;
  int ocg = blockIdx.x, b = blockIdx.y;
  int cy = tid >> 4, cx = tid & 15;
  f2 accP[4];
#pragma unroll
  for (int qp = 0; qp < 4; ++qp) accP[qp] = (f2){0.0f, 0.0f};

  for (int ict = 0; ict < 8; ++ict) {
    __syncthreads();
    for (int idx = tid; idx < 8 * 33 * 33; idx += 256) {
      int ic = idx / 1089;
      int rem = idx - ic * 1089;
      int rr = rem / 33, cc = rem - rr * 33;
      int iy = rr - 1, ix = cc - 1;
      float v = 0.0f;
      int icg = ict * 8 + ic;
      if (iy >= 0 && iy < 32 && ix >= 0 && ix < 32)
        v = h2[(((size_t)b * 64 + icg) * 32 + iy) * 32 + ix];
      tile[(ic * 33 + rr) * TS3 + cc] = v;
    }
    __syncthreads();
#pragma unroll
    for (int ic = 0; ic < 8; ++ic) {
      int icg = ict * 8 + ic;
      float in[3][3];
#pragma unroll
      for (int i = 0; i < 3; ++i) {
        const float2* r2 = reinterpret_cast<const float2*>(&tile[(ic * 33 + 2 * cy + i) * TS3 + 2 * cx]);
        float2 a = r2[0];
        in[i][0] = a.x; in[i][1] = a.y;
        in[i][2] = tile[(ic * 33 + 2 * cy + i) * TS3 + 2 * cx + 2];
      }
      const float* wic = w + ((size_t)(ocg * 8) * 64 + icg) * 9;
#pragma unroll
      for (int qp = 0; qp < 4; ++qp) {
        const float* wo0 = wic + (size_t)(2 * qp) * 64 * 9;
        const float* wo1 = wo0 + 64 * 9;
#pragma unroll
        for (int i = 0; i < 3; ++i)
#pragma unroll
          for (int j = 0; j < 3; ++j) {
            f2 wp = (f2){wo0[i * 3 + j], wo1[i * 3 + j]};
            f2 iv = (f2){in[i][j], in[i][j]};
            accP[qp] = __builtin_elementwise_fma(wp, iv, accP[qp]);
          }
      }
    }
  }
  int wvid = tid >> 6;
#pragma unroll
  for (int q = 0; q < 8; ++q) {
    int oc = ocg * 8 + q;
    float a = (q & 1) ? accP[q >> 1].y : accP[q >> 1].x;
    float inv = g[oc] / sqrtf(bv[oc] + 1e-5f);
    float sh  = cb[oc] * inv + bb[oc] - bm[oc] * inv;
    float v = fmaxf(a * inv + sh, 0.0f);
#pragma unroll
    for (int off = 32; off > 0; off >>= 1) v += __shfl_down(v, off);
    if ((tid & 63) == 0) ws3[q][wvid] = v;
  }
  __syncthreads();
  if (tid < 8)
    gap[(size_t)b * 128 + ocg * 8 + tid] =
        (ws3[tid][0] + ws3[tid][1] + ws3[tid][2] + ws3[tid][3]) * (1.0f / 256.0f);
}

// ------------------------------------------------- K7: FC1+ReLU+FC2+ReLU
__global__ __launch_bounds__(256) void k_fc(
    const float* __restrict__ gap,
    const float* __restrict__ w1, const float* __restrict__ b1,
    const float* __restrict__ w2, const float* __restrict__ b2,
    float* __restrict__ out) {
  __shared__ float gv[128], hv[256];
  int b = blockIdx.x, t = threadIdx.x;
  if (t < 128) gv[t] = gap[(size_t)b * 128 + t];
  __syncthreads();
  float a1 = b1[t];
  const float* wr = w1 + (size_t)t * 128;
  for (int k = 0; k < 128; ++k) a1 = fmaf(wr[k], gv[k], a1);
  hv[t] = fmaxf(a1, 0.0f);
  __syncthreads();
  if (t < 128) {
    float a2 = b2[t];
    const float* wr2 = w2 + (size_t)t * 256;
    for (int k = 0; k < 256; ++k) a2 = fmaf(wr2[k], hv[k], a2);
    out[(size_t)b * 128 + t] = fmaxf(a2, 0.0f);
  }
}

// ================================================================ launch
extern "C" void kernel_launch(void* const* d_in, const int* in_sizes, int n_in,
                              void* d_out, int out_size, void* d_ws, size_t ws_size,
                              hipStream_t stream) {
  (void)in_sizes; (void)n_in; (void)out_size; (void)ws_size;
  const float* x   = (const float*)d_in[0];
  const float* c1w = (const float*)d_in[1];
  const float* c1b = (const float*)d_in[2];
  const float* b1g = (const float*)d_in[3];
  const float* b1b = (const float*)d_in[4];
  const float* b1m = (const float*)d_in[5];
  const float* b1v = (const float*)d_in[6];
  const float* c2w = (const float*)d_in[7];
  const float* c2b = (const float*)d_in[8];
  const float* b2g = (const float*)d_in[9];
  const float* b2b = (const float*)d_in[10];
  const float* b2m = (const float*)d_in[11];
  const float* b2v = (const float*)d_in[12];
  const float* c3w = (const float*)d_in[13];
  const float* c3b = (const float*)d_in[14];
  const float* b3g = (const float*)d_in[15];
  const float* b3b = (const float*)d_in[16];
  const float* b3m = (const float*)d_in[17];
  const float* b3v = (const float*)d_in[18];
  const float* f1w = (const float*)d_in[19];
  const float* f1b = (const float*)d_in[20];
  const float* f2w = (const float*)d_in[21];
  const float* f2b = (const float*)d_in[22];
  float* out = (float*)d_out;

  char* ws = (char*)d_ws;
  float2* G     = (float2*)(ws + 0);
  float2* GT    = (float2*)(ws + 67633152ull);
  float*  S     = (float*) (ws + 135266304ull);
  double* stats = (double*)(ws + 202375168ull);
  float2* muinv = (float2*)(ws + 202376192ull);
  float*  gap   = (float*) (ws + 202376704ull);
  float*  h1    = (float*) (ws + 0);
  float*  h2    = (float*) (ws + 135266304ull);

  k_zero_stats<<<1, 128, 0, stream>>>(stats);
  k_rowfft   <<<dim3(128, 64), 256, 0, stream>>>(x, G);
  k_transpose<<<dim3(9, 16, 64), dim3(32, 8), 0, stream>>>(G, GT);
  k_colfft   <<<dim3(129, 64), 256, 0, stream>>>(GT, S, stats);
  k_stats    <<<1, 64, 0, stream>>>(stats, muinv);
  k_conv1    <<<dim3(64, 64), 256, 0, stream>>>(S, muinv, c1w, c1b, b1g, b1b, b1m, b1v, h1);
  k_conv2    <<<dim3(16, 64), 512, 0, stream>>>(h1, c2w, c2b, b2g, b2b, b2m, b2v, h2);
  k_conv3    <<<dim3(16, 64), 256, 0, stream>>>(h2, c3w, c3b, b3g, b3b, b3m, b3v, gap);
  k_fc       <<<64, 256, 0, stream>>>(gap, f1w, f1b, f2w, f2b, out);
}

// Round 11
// 900.349 us; speedup vs baseline: 1.0023x; 1.0023x over previous
//
#include <hip/hip_runtime.h>
#include <math.h>

#define PI_F 3.14159265358979323846f
#define KS 258   // padded column count of half-spectrum G (k in [0,256], stride 258)

typedef float f2 __attribute__((ext_vector_type(2)));

// ---------------------------------------------------------------- FFT core
// Two radix-2 stages fused per LDS round trip; u in [0,128) indexes the
// butterfly group. Called with re/im pointing at a 512-float segment.
// All threads of the block must call (uniform barriers).
__device__ __forceinline__ void fft512(float* re, float* im,
                                       const float* twr, const float* twi, int u) {
#pragma unroll
  for (int s = 0; s < 8; s += 2) {
    __syncthreads();
    {
      int h  = 1 << s;
      int j  = u & (h - 1);
      int a  = ((u >> s) << (s + 2)) + j;
      int i0 = a, i1 = a + h, i2 = a + 2 * h, i3 = a + 3 * h;
      float e0r = re[i0], e0i = im[i0];
      float e1r = re[i1], e1i = im[i1];
      float e2r = re[i2], e2i = im[i2];
      float e3r = re[i3], e3i = im[i3];
      int tis = j << (8 - s);
      float wsr = twr[tis], wsi = twi[tis];
      float t1r = e1r * wsr - e1i * wsi, t1i = e1r * wsi + e1i * wsr;
      float t3r = e3r * wsr - e3i * wsi, t3i = e3r * wsi + e3i * wsr;
      float b0r = e0r + t1r, b0i = e0i + t1i;
      float b1r = e0r - t1r, b1i = e0i - t1i;
      float b2r = e2r + t3r, b2i = e2i + t3i;
      float b3r = e2r - t3r, b3i = e2i - t3i;
      int ti0 = j << (7 - s);
      int ti1 = (j + h) << (7 - s);
      float w0r = twr[ti0], w0i = twi[ti0];
      float w1r = twr[ti1], w1i = twi[ti1];
      float u2r = b2r * w0r - b2i * w0i, u2i = b2r * w0i + b2i * w0r;
      float u3r = b3r * w1r - b3i * w1i, u3i = b3r * w1i + b3i * w1r;
      re[i0] = b0r + u2r; im[i0] = b0i + u2i;
      re[i2] = b0r - u2r; im[i2] = b0i - u2i;
      re[i1] = b1r + u3r; im[i1] = b1i + u3i;
      re[i3] = b1r - u3r; im[i3] = b1i - u3i;
    }
  }
  __syncthreads();
  {
#pragma unroll
    for (int k = 0; k < 2; ++k) {
      int i1 = u + k * 128;
      int i2 = i1 + 256;
      float wr = twr[i1], wi = twi[i1];
      float ur = re[i1], ui = im[i1];
      float vr = re[i2], vi = im[i2];
      float tr = vr * wr - vi * wi;
      float tq = vr * wi + vi * wr;
      re[i1] = ur + tr; im[i1] = ui + tq;
      re[i2] = ur - tr; im[i2] = ui - tq;
    }
  }
  __syncthreads();
}

__device__ __forceinline__ void init_tw(float* twr, float* twi, int t) {
  float s, c;
  sincosf(-2.0f * PI_F * (float)t * (1.0f / 512.0f), &s, &c);
  twr[t] = c; twi[t] = s;
}

// ------------------------------------------------- K1: gray + paired-row FFT (Hermitian pack)
// TWO packed FFTs per block (4 image rows), f = t>>7 selects the FFT.
__global__ __launch_bounds__(256) void k_rowfft(const float* __restrict__ x,
                                                float2* __restrict__ G) {
  __shared__ float re[1024], im[1024], twr[256], twi[256];
  int t = threadIdx.x;
  int q = blockIdx.x;          // 0..127
  int b = blockIdx.y;
  int f = t >> 7, u = t & 127;
  int r0 = 4 * q;
  const float* xb = x + ((size_t)b * 3 * 512 + r0) * 512;
  const float* xr = xb + (2 * f) * 512;   // row pair base for this FFT
  float* reb = re + 512 * f;
  float* imb = im + 512 * f;
#pragma unroll
  for (int j = 0; j < 4; ++j) {
    int p = u + 128 * j;
    float a = 0.299f * xr[p]        + 0.587f * xr[262144 + p]  + 0.114f * xr[524288 + p];
    float c = 0.299f * xr[512 + p]  + 0.587f * xr[262656 + p]  + 0.114f * xr[524800 + p];
    int rv = __brev((unsigned)p) >> 23;
    reb[rv] = a; imb[rv] = c;
  }
  init_tw(twr, twi, t);
  fft512(reb, imb, twr, twi, u);
  int r0p = r0 + 2 * f;
  float2* G0 = G + ((size_t)b * 512 + r0p) * KS;
  float2* G1 = G0 + KS;
  for (int k = u; k <= 256; k += 128) {
    int mk = (512 - k) & 511;
    float zr = reb[k], zi = imb[k];
    float mr = reb[mk], mi = imb[mk];
    G0[k] = make_float2(0.5f * (zr + mr), 0.5f * (zi - mi));
    G1[k] = make_float2(0.5f * (zi + mi), 0.5f * (mr - zr));
  }
}

// ------------------------------------------------- K2: column FFT + mag/log1p/fftshift + mirror + stats
// v4: TRANSPOSE FUSED. Each block stages a 512x8 column slab of G into LDS
// (coalesced row-segment reads; +1 pad -> stride-9 rows so column reads hit
// all 32 banks at 2 lanes/bank = conflict-free), then runs the 2-column FFT
// pipeline 4 times from the slab. Eliminates the GT round-trip entirely.
// Columns kc>256 (incl. G's pad col 257) are masked: compute discarded,
// no S writes, no stats contribution.
__global__ __launch_bounds__(256) void k_colfft(const float2* __restrict__ G,
                                                float* __restrict__ S,
                                                double* __restrict__ stats) {
  __shared__ float slr[512 * 9], sli[512 * 9];   // 36864 B
  __shared__ float re[1024], im[1024], twr[256], twi[256];
  __shared__ float ws1[4], ws2[4];
  int t = threadIdx.x;
  int b = blockIdx.y;
  int kc0 = blockIdx.x * 8;
  const float2* Gb = G + (size_t)b * 512 * KS;
#pragma unroll
  for (int i = 0; i < 16; ++i) {
    int idx = t + 256 * i;          // 0..4095
    int r = idx >> 3, c = idx & 7;
    int kc = kc0 + c;
    float2 v = make_float2(0.0f, 0.0f);
    if (kc < KS) v = Gb[(size_t)r * KS + kc];
    slr[r * 9 + c] = v.x;
    sli[r * 9 + c] = v.y;
  }
  init_tw(twr, twi, t);
  int f = t >> 7, u = t & 127;
  float* reb = re + 512 * f;
  float* imb = im + 512 * f;
  float s1 = 0.0f, s2 = 0.0f;
  float* Sb = S + (size_t)b * 262144;
  for (int cp = 0; cp < 4; ++cp) {
    int c = 2 * cp + f;
    int kc = kc0 + c;
    bool valid = (kc <= 256);
    __syncthreads();   // slab ready (cp=0) / prior round's re/im reads done
#pragma unroll
    for (int j = 0; j < 4; ++j) {
      int p = u + 128 * j;
      int rv = __brev((unsigned)p) >> 23;
      reb[rv] = slr[p * 9 + c];
      imb[rv] = sli[p * 9 + c];
    }
    fft512(reb, imb, twr, twi, u);
    int vrow = (kc + 256) & 511;
    bool mir = (kc >= 1) && (kc <= 255);
    float wgt = mir ? 2.0f : 1.0f;
#pragma unroll
    for (int j = 0; j < 4; ++j) {
      int k = u + 128 * j;
      float mm = log1pf(sqrtf(reb[k] * reb[k] + imb[k] * imb[k]));
      if (valid) {
        Sb[(size_t)vrow * 512 + ((k + 256) & 511)] = mm;
        if (mir) Sb[(size_t)(256 - kc) * 512 + ((256 - k) & 511)] = mm;
        s1 += wgt * mm; s2 += wgt * mm * mm;
      }
    }
  }
#pragma unroll
  for (int off = 32; off > 0; off >>= 1) {
    s1 += __shfl_down(s1, off);
    s2 += __shfl_down(s2, off);
  }
  int wvid = t >> 6;
  if ((t & 63) == 0) { ws1[wvid] = s1; ws2[wvid] = s2; }
  __syncthreads();
  if (t == 0) {
    atomicAdd(&stats[2 * b],     (double)(ws1[0] + ws1[1] + ws1[2] + ws1[3]));
    atomicAdd(&stats[2 * b + 1], (double)(ws2[0] + ws2[1] + ws2[2] + ws2[3]));
  }
}

__global__ void k_zero_stats(double* stats) {
  stats[threadIdx.x] = 0.0;
}

__global__ void k_stats(const double* __restrict__ stats, float2* __restrict__ muinv) {
  int i = threadIdx.x;  // 64
  double n  = 262144.0;
  double mu = stats[2 * i] / n;
  double va = stats[2 * i + 1] / n - mu * mu;
  if (va < 0.0) va = 0.0;
  double sd = sqrt(va);
  muinv[i] = make_float2((float)mu, (float)(1.0 / (sd + 1e-8)));
}

// ------------------------------------------------- K4: conv1(5x5,s2,p2) + BN + ReLU + maxpool2
#define TS1 68
__global__ __launch_bounds__(256) void k_conv1(
    const float* __restrict__ S, const float2* __restrict__ muinv,
    const float* __restrict__ w, const float* __restrict__ cb,
    const float* __restrict__ g, const float* __restrict__ bb,
    const float* __restrict__ bm, const float* __restrict__ bv,
    float* __restrict__ h1) {
  __shared__ float tile[67 * TS1];
  int b = blockIdx.y;
  int by = blockIdx.x >> 3, bx = blockIdx.x & 7;
  int y0 = by * 16, x0 = bx * 16;
  int h0 = 4 * y0 - 2, w0 = 4 * x0 - 2;
  float2 mi = muinv[b];
  const float* Sb = S + (size_t)b * 262144;
  for (int idx = threadIdx.x; idx < 67 * 67; idx += 256) {
    int wl = idx / 67, hl = idx - wl * 67;
    int hh = h0 + hl, ww = w0 + wl;
    float val = 0.0f;
    if (hh >= 0 && hh < 512 && ww >= 0 && ww < 512)
      val = (Sb[(size_t)ww * 512 + hh] - mi.x) * mi.y;
    tile[wl * TS1 + hl] = val;
  }
  __syncthreads();
  int ty = threadIdx.x >> 4, tx = threadIdx.x & 15;
  float in[7][7];
#pragma unroll
  for (int j = 0; j < 7; ++j)
#pragma unroll
    for (int i = 0; i < 7; ++i)
      in[i][j] = tile[(4 * tx + j) * TS1 + 4 * ty + i];
  f2 P[7][5];
#pragma unroll
  for (int r = 0; r < 7; ++r)
#pragma unroll
    for (int c = 0; c < 5; ++c)
      P[r][c] = (f2){in[r][c], in[r][c + 2]};
  int Y = y0 + ty, X = x0 + tx;
  for (int oc = 0; oc < 32; ++oc) {
    const float* wo = w + oc * 25;
    f2 aA = (f2){0.0f, 0.0f};
    f2 aB = (f2){0.0f, 0.0f};
#pragma unroll
    for (int dy = 0; dy < 5; ++dy)
#pragma unroll
      for (int dx = 0; dx < 5; ++dx) {
        float wv = wo[dy * 5 + dx];
        f2 wv2 = (f2){wv, wv};
        aA = __builtin_elementwise_fma(wv2, P[dy][dx],     aA);
        aB = __builtin_elementwise_fma(wv2, P[dy + 2][dx], aB);
      }
    float m   = fmaxf(fmaxf(aA.x, aA.y), fmaxf(aB.x, aB.y));
    float inv = g[oc] / sqrtf(bv[oc] + 1e-5f);
    float sh  = cb[oc] * inv + bb[oc] - bm[oc] * inv;
    h1[(((size_t)b * 32 + oc) * 128 + Y) * 128 + X] = fmaxf(m * inv + sh, 0.0f);
  }
}

// ------------------------------------------------- K5: conv2(3x3,s2,p1,32->64) + BN + ReLU + maxpool2
// v9: proven v7 schedule (single 38KB buffer, two barriers/phase, T14
// async-STAGE, pk-FMA) + v8's hoisted ict-invariant staging offsets.
#define TS2 36
__global__ __launch_bounds__(512) void k_conv2(
    const float* __restrict__ h1, const float* __restrict__ w,
    const float* __restrict__ cb, const float* __restrict__ g,
    const float* __restrict__ bb, const float* __restrict__ bm,
    const float* __restrict__ bv, float* __restrict__ h2) {
  __shared__ __attribute__((aligned(16))) float tile[8 * 33 * TS2];  // 38016 B
  int tid = threadIdx.x;
  int b = blockIdx.y;
  int rt = blockIdx.x >> 2, ct = blockIdx.x & 3;
  int ty0 = rt * 16, tx0 = ct * 16;
  int wv = tid >> 6;
  int lane = tid & 63;
  int qy = lane >> 3, qx = lane & 7;
  int iy0 = 2 * ty0 - 1, ix0 = 2 * tx0 - 1;
  int ocbase = wv * 8;
  f2 accA[8], accB[8];
#pragma unroll
  for (int q = 0; q < 8; ++q) {
    accA[q] = (f2){0.0f, 0.0f};
    accB[q] = (f2){0.0f, 0.0f};
  }

  // ---- precompute staging offsets (ict-invariant) ----
  int dsto[18], srco[18];
#pragma unroll
  for (int k = 0; k < 17; ++k) {
    int idx = tid + 512 * k;
    int ic = idx / 1089;
    int rem = idx - ic * 1089;
    int rr = rem / 33, cc = rem - rr * 33;
    int iy = iy0 + rr, ix = ix0 + cc;
    dsto[k] = (ic * 33 + rr) * TS2 + cc;
    srco[k] = (iy >= 0 && iy < 128 && ix >= 0 && ix < 128)
                  ? ((ic * 128 + iy) * 128 + ix) : -1;
  }
  {
    int idx = 8704 + tid;   // tail: only tid<8 writes
    int ic = idx / 1089;
    int rem = idx - ic * 1089;
    int rr = rem / 33, cc = rem - rr * 33;
    int iy = iy0 + rr, ix = ix0 + cc;
    dsto[17] = (ic * 33 + rr) * TS2 + cc;
    srco[17] = (tid < 8 && iy >= 0 && iy < 128 && ix >= 0 && ix < 128)
                   ? ((ic * 128 + iy) * 128 + ix) : -1;
  }
  const float* h1b = h1 + (size_t)b * 32 * 16384;

  float rv[18];
#define C2_LOADR(ICT)                                                          \
  {                                                                            \
    _Pragma("unroll")                                                          \
    for (int k = 0; k < 18; ++k) {                                             \
      float v = 0.0f;                                                          \
      if (srco[k] >= 0) v = h1b[(ICT) * 131072 + srco[k]];                     \
      rv[k] = v;                                                               \
    }                                                                          \
  }

#define C2_WRITER()                                                            \
  {                                                                            \
    _Pragma("unroll")                                                          \
    for (int k = 0; k < 17; ++k) tile[dsto[k]] = rv[k];                        \
    if (tid < 8) tile[dsto[17]] = rv[17];                                      \
  }

  C2_LOADR(0);
  for (int ict = 0; ict < 4; ++ict) {
    __syncthreads();          // previous compute done reading tile
    C2_WRITER();              // waits vmcnt for rv (issued a phase ago)
    __syncthreads();
    if (ict < 3) C2_LOADR(ict + 1);
    int rbase = 4 * qy, cbase = 4 * qx;
#pragma unroll
    for (int ic = 0; ic < 8; ++ic) {
      f2 P[5][3];
#pragma unroll
      for (int i = 0; i < 5; ++i) {
        int base = (ic * 33 + rbase + i) * TS2 + cbase;
        float4 a = *reinterpret_cast<const float4*>(&tile[base]);
        float b4 = tile[base + 4];
        P[i][0] = (f2){a.x, a.z};
        P[i][1] = (f2){a.y, a.w};
        P[i][2] = (f2){a.z, b4};
      }
      const float* wic = w + ((size_t)ocbase * 32 + ict * 8 + ic) * 9;
#pragma unroll
      for (int q = 0; q < 8; ++q) {
        const float* wo = wic + (size_t)q * 32 * 9;
#pragma unroll
        for (int dy = 0; dy < 3; ++dy)
#pragma unroll
          for (int dx = 0; dx < 3; ++dx) {
            float wvv = wo[dy * 3 + dx];
            f2 wv2 = (f2){wvv, wvv};
            accA[q] = __builtin_elementwise_fma(wv2, P[dy][dx],     accA[q]);
            accB[q] = __builtin_elementwise_fma(wv2, P[dy + 2][dx], accB[q]);
          }
      }
    }
  }
  int Yp = (ty0 >> 1) + qy, Xp = (tx0 >> 1) + qx;
#pragma unroll
  for (int q = 0; q < 8; ++q) {
    int oc = ocbase + q;
    float m   = fmaxf(fmaxf(accA[q].x, accA[q].y), fmaxf(accB[q].x, accB[q].y));
    float inv = g[oc] / sqrtf(bv[oc] + 1e-5f);
    float sh  = cb[oc] * inv + bb[oc] - bm[oc] * inv;
    h2[(((size_t)b * 64 + oc) * 32 + Yp) * 32 + Xp] = fmaxf(m * inv + sh, 0.0f);
  }
#undef C2_LOADR
#undef C2_WRITER
}

// ------------------------------------------------- K6: conv3(3x3,s2,p1,64->128) + BN + ReLU + GAP
#define TS3 34
__global__ __launch_bounds__(256) void k_conv3(
    const float* __restrict__ h2, const float* __restrict__ w,
    const float* __restrict__ cb, const float* __restrict__ g,
    const float* __restrict__ bb, const float* __restrict__ bm,
    const float* __restrict__ bv, float* __restrict__ gap) {
  __shared__ __attribute__((aligned(16))) float tile[8 * 33 * TS3];
  __shared__ float ws3[8][4];
  int tid = threadIdx.x;
  int ocg = blockIdx.x, b = blockIdx.y;
  int cy = tid >> 4, cx = tid & 15;
  f2 accP[4];
#pragma unroll
  for (int qp = 0; qp < 4; ++qp) accP[qp] = (f2){0.0f, 0.0f};

  for (int ict = 0; ict < 8; ++ict) {
    __syncthreads();
    for (int idx = tid; idx < 8 * 33 * 33; idx += 256) {
      int ic = idx / 1089;
      int rem = idx - ic * 1089;
      int rr = rem / 33, cc = rem - rr * 33;
      int iy = rr - 1, ix = cc - 1;
      float v = 0.0f;
      int icg = ict * 8 + ic;
      if (iy >= 0 && iy < 32 && ix >= 0 && ix < 32)
        v = h2[(((size_t)b * 64 + icg) * 32 + iy) * 32 + ix];
      tile[(ic * 33 + rr) * TS3 + cc] = v;
    }
    __syncthreads();
#pragma unroll
    for (int ic = 0; ic < 8; ++ic) {
      int icg = ict * 8 + ic;
      float in[3][3];
#pragma unroll
      for (int i = 0; i < 3; ++i) {
        const float2* r2 = reinterpret_cast<const float2*>(&tile[(ic * 33 + 2 * cy + i) * TS3 + 2 * cx]);
        float2 a = r2[0];
        in[i][0] = a.x; in[i][1] = a.y;
        in[i][2] = tile[(ic * 33 + 2 * cy + i) * TS3 + 2 * cx + 2];
      }
      const float* wic = w + ((size_t)(ocg * 8) * 64 + icg) * 9;
#pragma unroll
      for (int qp = 0; qp < 4; ++qp) {
        const float* wo0 = wic + (size_t)(2 * qp) * 64 * 9;
        const float* wo1 = wo0 + 64 * 9;
#pragma unroll
        for (int i = 0; i < 3; ++i)
#pragma unroll
          for (int j = 0; j < 3; ++j) {
            f2 wp = (f2){wo0[i * 3 + j], wo1[i * 3 + j]};
            f2 iv = (f2){in[i][j], in[i][j]};
            accP[qp] = __builtin_elementwise_fma(wp, iv, accP[qp]);
          }
      }
    }
  }
  int wvid = tid >> 6;
#pragma unroll
  for (int q = 0; q < 8; ++q) {
    int oc = ocg * 8 + q;
    float a = (q & 1) ? accP[q >> 1].y : accP[q >> 1].x;
    float inv = g[oc] / sqrtf(bv[oc] + 1e-5f);
    float sh  = cb[oc] * inv + bb[oc] - bm[oc] * inv;
    float v = fmaxf(a * inv + sh, 0.0f);
#pragma unroll
    for (int off = 32; off > 0; off >>= 1) v += __shfl_down(v, off);
    if ((tid & 63) == 0) ws3[q][wvid] = v;
  }
  __syncthreads();
  if (tid < 8)
    gap[(size_t)b * 128 + ocg * 8 + tid] =
        (ws3[tid][0] + ws3[tid][1] + ws3[tid][2] + ws3[tid][3]) * (1.0f / 256.0f);
}

// ------------------------------------------------- K7: FC1+ReLU+FC2+ReLU
__global__ __launch_bounds__(256) void k_fc(
    const float* __restrict__ gap,
    const float* __restrict__ w1, const float* __restrict__ b1,
    const float* __restrict__ w2, const float* __restrict__ b2,
    float* __restrict__ out) {
  __shared__ float gv[128], hv[256];
  int b = blockIdx.x, t = threadIdx.x;
  if (t < 128) gv[t] = gap[(size_t)b * 128 + t];
  __syncthreads();
  float a1 = b1[t];
  const float* wr = w1 + (size_t)t * 128;
  for (int k = 0; k < 128; ++k) a1 = fmaf(wr[k], gv[k], a1);
  hv[t] = fmaxf(a1, 0.0f);
  __syncthreads();
  if (t < 128) {
    float a2 = b2[t];
    const float* wr2 = w2 + (size_t)t * 256;
    for (int k = 0; k < 256; ++k) a2 = fmaf(wr2[k], hv[k], a2);
    out[(size_t)b * 128 + t] = fmaxf(a2, 0.0f);
  }
}

// ================================================================ launch
extern "C" void kernel_launch(void* const* d_in, const int* in_sizes, int n_in,
                              void* d_out, int out_size, void* d_ws, size_t ws_size,
                              hipStream_t stream) {
  (void)in_sizes; (void)n_in; (void)out_size; (void)ws_size;
  const float* x   = (const float*)d_in[0];
  const float* c1w = (const float*)d_in[1];
  const float* c1b = (const float*)d_in[2];
  const float* b1g = (const float*)d_in[3];
  const float* b1b = (const float*)d_in[4];
  const float* b1m = (const float*)d_in[5];
  const float* b1v = (const float*)d_in[6];
  const float* c2w = (const float*)d_in[7];
  const float* c2b = (const float*)d_in[8];
  const float* b2g = (const float*)d_in[9];
  const float* b2b = (const float*)d_in[10];
  const float* b2m = (const float*)d_in[11];
  const float* b2v = (const float*)d_in[12];
  const float* c3w = (const float*)d_in[13];
  const float* c3b = (const float*)d_in[14];
  const float* b3g = (const float*)d_in[15];
  const float* b3b = (const float*)d_in[16];
  const float* b3m = (const float*)d_in[17];
  const float* b3v = (const float*)d_in[18];
  const float* f1w = (const float*)d_in[19];
  const float* f1b = (const float*)d_in[20];
  const float* f2w = (const float*)d_in[21];
  const float* f2b = (const float*)d_in[22];
  float* out = (float*)d_out;

  char* ws = (char*)d_ws;
  float2* G     = (float2*)(ws + 0);
  float*  S     = (float*) (ws + 135266304ull);
  double* stats = (double*)(ws + 202375168ull);
  float2* muinv = (float2*)(ws + 202376192ull);
  float*  gap   = (float*) (ws + 202376704ull);
  float*  h1    = (float*) (ws + 67633152ull);   // after G's live range would
                                                 // overlap colfft; use old GT slot
  float*  h2    = (float*) (ws + 0);             // G dead after colfft

  k_zero_stats<<<1, 128, 0, stream>>>(stats);
  k_rowfft   <<<dim3(128, 64), 256, 0, stream>>>(x, G);
  k_colfft   <<<dim3(33, 64), 256, 0, stream>>>(G, S, stats);
  k_stats    <<<1, 64, 0, stream>>>(stats, muinv);
  k_conv1    <<<dim3(64, 64), 256, 0, stream>>>(S, muinv, c1w, c1b, b1g, b1b, b1m, b1v, h1);
  k_conv2    <<<dim3(16, 64), 512, 0, stream>>>(h1, c2w, c2b, b2g, b2b, b2m, b2v, h2);
  k_conv3    <<<dim3(16, 64), 256, 0, stream>>>(h2, c3w, c3b, b3g, b3b, b3m, b3v, gap);
  k_fc       <<<64, 256, 0, stream>>>(gap, f1w, f1b, f2w, f2b, out);
}

// Round 12
// 885.979 us; speedup vs baseline: 1.0186x; 1.0162x over previous
//
#include <hip/hip_runtime.h>
#include <math.h>

#define PI_F 3.14159265358979323846f
#define KS 258   // padded column count of half-spectrum G (k in [0,256], stride 258)

typedef float f2 __attribute__((ext_vector_type(2)));

// ---------------------------------------------------------------- FFT core
// Two radix-2 stages fused per LDS round trip; u in [0,128) indexes the
// butterfly group. re/im point at a PADDED 528-float segment; logical index
// i lives at PADI(i) = i + (i>>5) (1 pad word per 32 -> stage-0 accesses
// spread over all 32 banks at 2 lanes/bank = conflict-free; was 8-way).
// All threads of the block must call (uniform barriers).
#define PADI(i) ((i) + ((i) >> 5))
#define FSEG 528

__device__ __forceinline__ void fft512(float* re, float* im,
                                       const float* twr, const float* twi, int u) {
#pragma unroll
  for (int s = 0; s < 8; s += 2) {
    __syncthreads();
    {
      int h  = 1 << s;
      int j  = u & (h - 1);
      int a  = ((u >> s) << (s + 2)) + j;
      int i0 = PADI(a), i1 = PADI(a + h), i2 = PADI(a + 2 * h), i3 = PADI(a + 3 * h);
      float e0r = re[i0], e0i = im[i0];
      float e1r = re[i1], e1i = im[i1];
      float e2r = re[i2], e2i = im[i2];
      float e3r = re[i3], e3i = im[i3];
      int tis = j << (8 - s);
      float wsr = twr[tis], wsi = twi[tis];
      float t1r = e1r * wsr - e1i * wsi, t1i = e1r * wsi + e1i * wsr;
      float t3r = e3r * wsr - e3i * wsi, t3i = e3r * wsi + e3i * wsr;
      float b0r = e0r + t1r, b0i = e0i + t1i;
      float b1r = e0r - t1r, b1i = e0i - t1i;
      float b2r = e2r + t3r, b2i = e2i + t3i;
      float b3r = e2r - t3r, b3i = e2i - t3i;
      int ti0 = j << (7 - s);
      int ti1 = (j + h) << (7 - s);
      float w0r = twr[ti0], w0i = twi[ti0];
      float w1r = twr[ti1], w1i = twi[ti1];
      float u2r = b2r * w0r - b2i * w0i, u2i = b2r * w0i + b2i * w0r;
      float u3r = b3r * w1r - b3i * w1i, u3i = b3r * w1i + b3i * w1r;
      re[i0] = b0r + u2r; im[i0] = b0i + u2i;
      re[i2] = b0r - u2r; im[i2] = b0i - u2i;
      re[i1] = b1r + u3r; im[i1] = b1i + u3i;
      re[i3] = b1r - u3r; im[i3] = b1i - u3i;
    }
  }
  __syncthreads();
  {
#pragma unroll
    for (int k = 0; k < 2; ++k) {
      int kl = u + k * 128;          // logical index (also twiddle index)
      int i1 = PADI(kl);
      int i2 = PADI(kl + 256);
      float wr = twr[kl], wi = twi[kl];
      float ur = re[i1], ui = im[i1];
      float vr = re[i2], vi = im[i2];
      float tr = vr * wr - vi * wi;
      float tq = vr * wi + vi * wr;
      re[i1] = ur + tr; im[i1] = ui + tq;
      re[i2] = ur - tr; im[i2] = ui - tq;
    }
  }
  __syncthreads();
}

__device__ __forceinline__ void init_tw(float* twr, float* twi, int t) {
  float s, c;
  sincosf(-2.0f * PI_F * (float)t * (1.0f / 512.0f), &s, &c);
  twr[t] = c; twi[t] = s;
}

// ------------------------------------------------- K1: gray + paired-row FFT (Hermitian pack)
// TWO packed FFTs per block (4 image rows), f = t>>7 selects the FFT.
__global__ __launch_bounds__(256) void k_rowfft(const float* __restrict__ x,
                                                float2* __restrict__ G) {
  __shared__ float re[2 * FSEG], im[2 * FSEG], twr[256], twi[256];
  int t = threadIdx.x;
  int q = blockIdx.x;          // 0..127
  int b = blockIdx.y;
  int f = t >> 7, u = t & 127;
  int r0 = 4 * q;
  const float* xb = x + ((size_t)b * 3 * 512 + r0) * 512;
  const float* xr = xb + (2 * f) * 512;   // row pair base for this FFT
  float* reb = re + FSEG * f;
  float* imb = im + FSEG * f;
#pragma unroll
  for (int j = 0; j < 4; ++j) {
    int p = u + 128 * j;
    float a = 0.299f * xr[p]        + 0.587f * xr[262144 + p]  + 0.114f * xr[524288 + p];
    float c = 0.299f * xr[512 + p]  + 0.587f * xr[262656 + p]  + 0.114f * xr[524800 + p];
    int rv = __brev((unsigned)p) >> 23;
    reb[PADI(rv)] = a; imb[PADI(rv)] = c;
  }
  init_tw(twr, twi, t);
  fft512(reb, imb, twr, twi, u);
  int r0p = r0 + 2 * f;
  float2* G0 = G + ((size_t)b * 512 + r0p) * KS;
  float2* G1 = G0 + KS;
  for (int k = u; k <= 256; k += 128) {
    int mk = (512 - k) & 511;
    float zr = reb[PADI(k)],  zi = imb[PADI(k)];
    float mr = reb[PADI(mk)], mi = imb[PADI(mk)];
    G0[k] = make_float2(0.5f * (zr + mr), 0.5f * (zi - mi));
    G1[k] = make_float2(0.5f * (zi + mi), 0.5f * (mr - zr));
  }
}

// ------------------------------------------------- K2: column FFT + mag/log1p/fftshift + mirror + stats
// TRANSPOSE FUSED (round-11): 512x8 column slab of G staged in LDS
// (stride-9 rows), 2-column FFT pipeline x4 from the slab. Columns kc>256
// masked (no S writes, no stats).
__global__ __launch_bounds__(256) void k_colfft(const float2* __restrict__ G,
                                                float* __restrict__ S,
                                                double* __restrict__ stats) {
  __shared__ float slr[512 * 9], sli[512 * 9];   // 36864 B
  __shared__ float re[2 * FSEG], im[2 * FSEG], twr[256], twi[256];
  __shared__ float ws1[4], ws2[4];
  int t = threadIdx.x;
  int b = blockIdx.y;
  int kc0 = blockIdx.x * 8;
  const float2* Gb = G + (size_t)b * 512 * KS;
#pragma unroll
  for (int i = 0; i < 16; ++i) {
    int idx = t + 256 * i;          // 0..4095
    int r = idx >> 3, c = idx & 7;
    int kc = kc0 + c;
    float2 v = make_float2(0.0f, 0.0f);
    if (kc < KS) v = Gb[(size_t)r * KS + kc];
    slr[r * 9 + c] = v.x;
    sli[r * 9 + c] = v.y;
  }
  init_tw(twr, twi, t);
  int f = t >> 7, u = t & 127;
  float* reb = re + FSEG * f;
  float* imb = im + FSEG * f;
  float s1 = 0.0f, s2 = 0.0f;
  float* Sb = S + (size_t)b * 262144;
  for (int cp = 0; cp < 4; ++cp) {
    int c = 2 * cp + f;
    int kc = kc0 + c;
    bool valid = (kc <= 256);
    __syncthreads();   // slab ready (cp=0) / prior round's re/im reads done
#pragma unroll
    for (int j = 0; j < 4; ++j) {
      int p = u + 128 * j;
      int rv = __brev((unsigned)p) >> 23;
      reb[PADI(rv)] = slr[p * 9 + c];
      imb[PADI(rv)] = sli[p * 9 + c];
    }
    fft512(reb, imb, twr, twi, u);
    int vrow = (kc + 256) & 511;
    bool mir = (kc >= 1) && (kc <= 255);
    float wgt = mir ? 2.0f : 1.0f;
#pragma unroll
    for (int j = 0; j < 4; ++j) {
      int k = u + 128 * j;
      int kp = PADI(k);
      float mm = log1pf(sqrtf(reb[kp] * reb[kp] + imb[kp] * imb[kp]));
      if (valid) {
        Sb[(size_t)vrow * 512 + ((k + 256) & 511)] = mm;
        if (mir) Sb[(size_t)(256 - kc) * 512 + ((256 - k) & 511)] = mm;
        s1 += wgt * mm; s2 += wgt * mm * mm;
      }
    }
  }
#pragma unroll
  for (int off = 32; off > 0; off >>= 1) {
    s1 += __shfl_down(s1, off);
    s2 += __shfl_down(s2, off);
  }
  int wvid = t >> 6;
  if ((t & 63) == 0) { ws1[wvid] = s1; ws2[wvid] = s2; }
  __syncthreads();
  if (t == 0) {
    atomicAdd(&stats[2 * b],     (double)(ws1[0] + ws1[1] + ws1[2] + ws1[3]));
    atomicAdd(&stats[2 * b + 1], (double)(ws2[0] + ws2[1] + ws2[2] + ws2[3]));
  }
}

__global__ void k_zero_stats(double* stats) {
  stats[threadIdx.x] = 0.0;
}

__global__ void k_stats(const double* __restrict__ stats, float2* __restrict__ muinv) {
  int i = threadIdx.x;  // 64
  double n  = 262144.0;
  double mu = stats[2 * i] / n;
  double va = stats[2 * i + 1] / n - mu * mu;
  if (va < 0.0) va = 0.0;
  double sd = sqrt(va);
  muinv[i] = make_float2((float)mu, (float)(1.0 / (sd + 1e-8)));
}

// ------------------------------------------------- K4: conv1(5x5,s2,p2) + BN + ReLU + maxpool2
#define TS1 68
__global__ __launch_bounds__(256) void k_conv1(
    const float* __restrict__ S, const float2* __restrict__ muinv,
    const float* __restrict__ w, const float* __restrict__ cb,
    const float* __restrict__ g, const float* __restrict__ bb,
    const float* __restrict__ bm, const float* __restrict__ bv,
    float* __restrict__ h1) {
  __shared__ float tile[67 * TS1];
  int b = blockIdx.y;
  int by = blockIdx.x >> 3, bx = blockIdx.x & 7;
  int y0 = by * 16, x0 = bx * 16;
  int h0 = 4 * y0 - 2, w0 = 4 * x0 - 2;
  float2 mi = muinv[b];
  const float* Sb = S + (size_t)b * 262144;
  for (int idx = threadIdx.x; idx < 67 * 67; idx += 256) {
    int wl = idx / 67, hl = idx - wl * 67;
    int hh = h0 + hl, ww = w0 + wl;
    float val = 0.0f;
    if (hh >= 0 && hh < 512 && ww >= 0 && ww < 512)
      val = (Sb[(size_t)ww * 512 + hh] - mi.x) * mi.y;
    tile[wl * TS1 + hl] = val;
  }
  __syncthreads();
  int ty = threadIdx.x >> 4, tx = threadIdx.x & 15;
  float in[7][7];
#pragma unroll
  for (int j = 0; j < 7; ++j)
#pragma unroll
    for (int i = 0; i < 7; ++i)
      in[i][j] = tile[(4 * tx + j) * TS1 + 4 * ty + i];
  f2 P[7][5];
#pragma unroll
  for (int r = 0; r < 7; ++r)
#pragma unroll
    for (int c = 0; c < 5; ++c)
      P[r][c] = (f2){in[r][c], in[r][c + 2]};
  int Y = y0 + ty, X = x0 + tx;
  for (int oc = 0; oc < 32; ++oc) {
    const float* wo = w + oc * 25;
    f2 aA = (f2){0.0f, 0.0f};
    f2 aB = (f2){0.0f, 0.0f};
#pragma unroll
    for (int dy = 0; dy < 5; ++dy)
#pragma unroll
      for (int dx = 0; dx < 5; ++dx) {
        float wv = wo[dy * 5 + dx];
        f2 wv2 = (f2){wv, wv};
        aA = __builtin_elementwise_fma(wv2, P[dy][dx],     aA);
        aB = __builtin_elementwise_fma(wv2, P[dy + 2][dx], aB);
      }
    float m   = fmaxf(fmaxf(aA.x, aA.y), fmaxf(aB.x, aB.y));
    float inv = g[oc] / sqrtf(bv[oc] + 1e-5f);
    float sh  = cb[oc] * inv + bb[oc] - bm[oc] * inv;
    h1[(((size_t)b * 32 + oc) * 128 + Y) * 128 + X] = fmaxf(m * inv + sh, 0.0f);
  }
}

// ------------------------------------------------- K5: conv2(3x3,s2,p1,32->64) + BN + ReLU + maxpool2
// v9: proven v7 schedule (single 38KB buffer, two barriers/phase, T14
// async-STAGE, pk-FMA) + hoisted ict-invariant staging offsets.
#define TS2 36
__global__ __launch_bounds__(512) void k_conv2(
    const float* __restrict__ h1, const float* __restrict__ w,
    const float* __restrict__ cb, const float* __restrict__ g,
    const float* __restrict__ bb, const float* __restrict__ bm,
    const float* __restrict__ bv, float* __restrict__ h2) {
  __shared__ __attribute__((aligned(16))) float tile[8 * 33 * TS2];  // 38016 B
  int tid = threadIdx.x;
  int b = blockIdx.y;
  int rt = blockIdx.x >> 2, ct = blockIdx.x & 3;
  int ty0 = rt * 16, tx0 = ct * 16;
  int wv = tid >> 6;
  int lane = tid & 63;
  int qy = lane >> 3, qx = lane & 7;
  int iy0 = 2 * ty0 - 1, ix0 = 2 * tx0 - 1;
  int ocbase = wv * 8;
  f2 accA[8], accB[8];
#pragma unroll
  for (int q = 0; q < 8; ++q) {
    accA[q] = (f2){0.0f, 0.0f};
    accB[q] = (f2){0.0f, 0.0f};
  }

  // ---- precompute staging offsets (ict-invariant) ----
  int dsto[18], srco[18];
#pragma unroll
  for (int k = 0; k < 17; ++k) {
    int idx = tid + 512 * k;
    int ic = idx / 1089;
    int rem = idx - ic * 1089;
    int rr = rem / 33, cc = rem - rr * 33;
    int iy = iy0 + rr, ix = ix0 + cc;
    dsto[k] = (ic * 33 + rr) * TS2 + cc;
    srco[k] = (iy >= 0 && iy < 128 && ix >= 0 && ix < 128)
                  ? ((ic * 128 + iy) * 128 + ix) : -1;
  }
  {
    int idx = 8704 + tid;   // tail: only tid<8 writes
    int ic = idx / 1089;
    int rem = idx - ic * 1089;
    int rr = rem / 33, cc = rem - rr * 33;
    int iy = iy0 + rr, ix = ix0 + cc;
    dsto[17] = (ic * 33 + rr) * TS2 + cc;
    srco[17] = (tid < 8 && iy >= 0 && iy < 128 && ix >= 0 && ix < 128)
                   ? ((ic * 128 + iy) * 128 + ix) : -1;
  }
  const float* h1b = h1 + (size_t)b * 32 * 16384;

  float rv[18];
#define C2_LOADR(ICT)                                                          \
  {                                                                            \
    _Pragma("unroll")                                                          \
    for (int k = 0; k < 18; ++k) {                                             \
      float v = 0.0f;                                                          \
      if (srco[k] >= 0) v = h1b[(ICT) * 131072 + srco[k]];                     \
      rv[k] = v;                                                               \
    }                                                                          \
  }

#define C2_WRITER()                                                            \
  {                                                                            \
    _Pragma("unroll")                                                          \
    for (int k = 0; k < 17; ++k) tile[dsto[k]] = rv[k];                        \
    if (tid < 8) tile[dsto[17]] = rv[17];                                      \
  }

  C2_LOADR(0);
  for (int ict = 0; ict < 4; ++ict) {
    __syncthreads();          // previous compute done reading tile
    C2_WRITER();              // waits vmcnt for rv (issued a phase ago)
    __syncthreads();
    if (ict < 3) C2_LOADR(ict + 1);
    int rbase = 4 * qy, cbase = 4 * qx;
#pragma unroll
    for (int ic = 0; ic < 8; ++ic) {
      f2 P[5][3];
#pragma unroll
      for (int i = 0; i < 5; ++i) {
        int base = (ic * 33 + rbase + i) * TS2 + cbase;
        float4 a = *reinterpret_cast<const float4*>(&tile[base]);
        float b4 = tile[base + 4];
        P[i][0] = (f2){a.x, a.z};
        P[i][1] = (f2){a.y, a.w};
        P[i][2] = (f2){a.z, b4};
      }
      const float* wic = w + ((size_t)ocbase * 32 + ict * 8 + ic) * 9;
#pragma unroll
      for (int q = 0; q < 8; ++q) {
        const float* wo = wic + (size_t)q * 32 * 9;
#pragma unroll
        for (int dy = 0; dy < 3; ++dy)
#pragma unroll
          for (int dx = 0; dx < 3; ++dx) {
            float wvv = wo[dy * 3 + dx];
            f2 wv2 = (f2){wvv, wvv};
            accA[q] = __builtin_elementwise_fma(wv2, P[dy][dx],     accA[q]);
            accB[q] = __builtin_elementwise_fma(wv2, P[dy + 2][dx], accB[q]);
          }
      }
    }
  }
  int Yp = (ty0 >> 1) + qy, Xp = (tx0 >> 1) + qx;
#pragma unroll
  for (int q = 0; q < 8; ++q) {
    int oc = ocbase + q;
    float m   = fmaxf(fmaxf(accA[q].x, accA[q].y), fmaxf(accB[q].x, accB[q].y));
    float inv = g[oc] / sqrtf(bv[oc] + 1e-5f);
    float sh  = cb[oc] * inv + bb[oc] - bm[oc] * inv;
    h2[(((size_t)b * 64 + oc) * 32 + Yp) * 32 + Xp] = fmaxf(m * inv + sh, 0.0f);
  }
#undef C2_LOADR
#undef C2_WRITER
}

// ------------------------------------------------- K6: conv3(3x3,s2,p1,64->128) + BN + ReLU + GAP
#define TS3 34
__global__ __launch_bounds__(256) void k_conv3(
    const float* __restrict__ h2, const float* __restrict__ w,
    const float* __restrict__ cb, const float* __restrict__ g,
    const float* __restrict__ bb, const float* __restrict__ bm,
    const float* __restrict__ bv, float* __restrict__ gap) {
  __shared__ __attribute__((aligned(16))) float tile[8 * 33 * TS3];
  __shared__ float ws3[8][4];
  int tid = threadIdx.x;
  int ocg = blockIdx.x, b = blockIdx.y;
  int cy = tid >> 4, cx = tid & 15;
  f2 accP[4];
#pragma unroll
  for (int qp = 0; qp < 4; ++qp) accP[qp] = (f2){0.0f, 0.0f};

  for (int ict = 0; ict < 8; ++ict) {
    __syncthreads();
    for (int idx = tid; idx < 8 * 33 * 33; idx += 256) {
      int ic = idx / 1089;
      int rem = idx - ic * 1089;
      int rr = rem / 33, cc = rem - rr * 33;
      int iy = rr - 1, ix = cc - 1;
      float v = 0.0f;
      int icg = ict * 8 + ic;
      if (iy >= 0 && iy < 32 && ix >= 0 && ix < 32)
        v = h2[(((size_t)b * 64 + icg) * 32 + iy) * 32 + ix];
      tile[(ic * 33 + rr) * TS3 + cc] = v;
    }
    __syncthreads();
#pragma unroll
    for (int ic = 0; ic < 8; ++ic) {
      int icg = ict * 8 + ic;
      float in[3][3];
#pragma unroll
      for (int i = 0; i < 3; ++i) {
        const float2* r2 = reinterpret_cast<const float2*>(&tile[(ic * 33 + 2 * cy + i) * TS3 + 2 * cx]);
        float2 a = r2[0];
        in[i][0] = a.x; in[i][1] = a.y;
        in[i][2] = tile[(ic * 33 + 2 * cy + i) * TS3 + 2 * cx + 2];
      }
      const float* wic = w + ((size_t)(ocg * 8) * 64 + icg) * 9;
#pragma unroll
      for (int qp = 0; qp < 4; ++qp) {
        const float* wo0 = wic + (size_t)(2 * qp) * 64 * 9;
        const float* wo1 = wo0 + 64 * 9;
#pragma unroll
        for (int i = 0; i < 3; ++i)
#pragma unroll
          for (int j = 0; j < 3; ++j) {
            f2 wp = (f2){wo0[i * 3 + j], wo1[i * 3 + j]};
            f2 iv = (f2){in[i][j], in[i][j]};
            accP[qp] = __builtin_elementwise_fma(wp, iv, accP[qp]);
          }
      }
    }
  }
  int wvid = tid >> 6;
#pragma unroll
  for (int q = 0; q < 8; ++q) {
    int oc = ocg * 8 + q;
    float a = (q & 1) ? accP[q >> 1].y : accP[q >> 1].x;
    float inv = g[oc] / sqrtf(bv[oc] + 1e-5f);
    float sh  = cb[oc] * inv + bb[oc] - bm[oc] * inv;
    float v = fmaxf(a * inv + sh, 0.0f);
#pragma unroll
    for (int off = 32; off > 0; off >>= 1) v += __shfl_down(v, off);
    if ((tid & 63) == 0) ws3[q][wvid] = v;
  }
  __syncthreads();
  if (tid < 8)
    gap[(size_t)b * 128 + ocg * 8 + tid] =
        (ws3[tid][0] + ws3[tid][1] + ws3[tid][2] + ws3[tid][3]) * (1.0f / 256.0f);
}

// ------------------------------------------------- K7: FC1+ReLU+FC2+ReLU
__global__ __launch_bounds__(256) void k_fc(
    const float* __restrict__ gap,
    const float* __restrict__ w1, const float* __restrict__ b1,
    const float* __restrict__ w2, const float* __restrict__ b2,
    float* __restrict__ out) {
  __shared__ float gv[128], hv[256];
  int b = blockIdx.x, t = threadIdx.x;
  if (t < 128) gv[t] = gap[(size_t)b * 128 + t];
  __syncthreads();
  float a1 = b1[t];
  const float* wr = w1 + (size_t)t * 128;
  for (int k = 0; k < 128; ++k) a1 = fmaf(wr[k], gv[k], a1);
  hv[t] = fmaxf(a1, 0.0f);
  __syncthreads();
  if (t < 128) {
    float a2 = b2[t];
    const float* wr2 = w2 + (size_t)t * 256;
    for (int k = 0; k < 256; ++k) a2 = fmaf(wr2[k], hv[k], a2);
    out[(size_t)b * 128 + t] = fmaxf(a2, 0.0f);
  }
}

// ================================================================ launch
extern "C" void kernel_launch(void* const* d_in, const int* in_sizes, int n_in,
                              void* d_out, int out_size, void* d_ws, size_t ws_size,
                              hipStream_t stream) {
  (void)in_sizes; (void)n_in; (void)out_size; (void)ws_size;
  const float* x   = (const float*)d_in[0];
  const float* c1w = (const float*)d_in[1];
  const float* c1b = (const float*)d_in[2];
  const float* b1g = (const float*)d_in[3];
  const float* b1b = (const float*)d_in[4];
  const float* b1m = (const float*)d_in[5];
  const float* b1v = (const float*)d_in[6];
  const float* c2w = (const float*)d_in[7];
  const float* c2b = (const float*)d_in[8];
  const float* b2g = (const float*)d_in[9];
  const float* b2b = (const float*)d_in[10];
  const float* b2m = (const float*)d_in[11];
  const float* b2v = (const float*)d_in[12];
  const float* c3w = (const float*)d_in[13];
  const float* c3b = (const float*)d_in[14];
  const float* b3g = (const float*)d_in[15];
  const float* b3b = (const float*)d_in[16];
  const float* b3m = (const float*)d_in[17];
  const float* b3v = (const float*)d_in[18];
  const float* f1w = (const float*)d_in[19];
  const float* f1b = (const float*)d_in[20];
  const float* f2w = (const float*)d_in[21];
  const float* f2b = (const float*)d_in[22];
  float* out = (float*)d_out;

  char* ws = (char*)d_ws;
  float2* G     = (float2*)(ws + 0);
  float*  S     = (float*) (ws + 135266304ull);
  double* stats = (double*)(ws + 202375168ull);
  float2* muinv = (float2*)(ws + 202376192ull);
  float*  gap   = (float*) (ws + 202376704ull);
  float*  h1    = (float*) (ws + 67633152ull);   // old GT slot (G live only until colfft)
  float*  h2    = (float*) (ws + 0);             // G dead after colfft

  k_zero_stats<<<1, 128, 0, stream>>>(stats);
  k_rowfft   <<<dim3(128, 64), 256, 0, stream>>>(x, G);
  k_colfft   <<<dim3(33, 64), 256, 0, stream>>>(G, S, stats);
  k_stats    <<<1, 64, 0, stream>>>(stats, muinv);
  k_conv1    <<<dim3(64, 64), 256, 0, stream>>>(S, muinv, c1w, c1b, b1g, b1b, b1m, b1v, h1);
  k_conv2    <<<dim3(16, 64), 512, 0, stream>>>(h1, c2w, c2b, b2g, b2b, b2m, b2v, h2);
  k_conv3    <<<dim3(16, 64), 256, 0, stream>>>(h2, c3w, c3b, b3g, b3b, b3m, b3v, gap);
  k_fc       <<<64, 256, 0, stream>>>(gap, f1w, f1b, f2w, f2b, out);
}